// Round 5
// baseline (505.879 us; speedup 1.0000x reference)
//
#include <hip/hip_runtime.h>

#define NG   256   // graphs (= grid)
#define NP   512   // nodes per graph
#define EPG  8192  // edges per graph
#define FDIM 128
#define STB  36    // bufB stride (floats): 144 B, 16B-aligned; random-row starts spread 8 bank-groups

// ---- LDS layout (bytes) ----
#define OFF_STAGE 0                        // x chunk stage: 512 rows x 128 B = 65536
#define OFF_BUFB  65536                    // f32[512*36] = 73728 -> ends 139264
#define OFF_CSR   139264                   // u16[8192] = 16384 -> 155648
#define OFF_OFFS  155648                   // u16[513] -> 1032  -> 156680
#define OFF_WT    156680                   // u32[8] = 32       -> 156712
#define OFF_CUR   156712                   // u32[512] = 2048   -> 158760 (lin3S overlay later)
#define OFF_DCNT  158760                   // u32[512] = 2048   -> 160808
#define OFF_NRM   160808                   // f32[512] = 2048   -> 162856
#define SMEM_SZ   162856                   // <= 163840

// overlays
#define OFF_KEY  OFF_CSR                   // f32[512] (csr dead after layer-3 agg)
#define OFF_IDX  (OFF_CSR + 2048)          // u32[512]
#define OFF_L3   OFF_CUR                   // f32[512] (cursors dead after CSR build)
// tail arrays live in the dead stage region (float offsets from stage base)
#define FO_FEAT 0                          // f32[97*64] = 6208 floats
#define FO_C1   6208                       // f32[16*64]
#define FO_P    7232                       // f32[16*32]
#define FO_C2   7744                       // f32[896]
#define FO_HID  8640                       // f32[128]

__global__ __launch_bounds__(1024, 4) void dgcnn_fused(
    const float* __restrict__ x,
    const float* __restrict__ W0, const float* __restrict__ b0,
    const float* __restrict__ W1, const float* __restrict__ b1,
    const float* __restrict__ W2, const float* __restrict__ b2,
    const float* __restrict__ W3, const float* __restrict__ b3,
    const float* __restrict__ c1w, const float* __restrict__ c1b,
    const float* __restrict__ c2w, const float* __restrict__ c2b,
    const float* __restrict__ d1w, const float* __restrict__ d1b,
    const float* __restrict__ d2w, const float* __restrict__ d2b,
    const int* __restrict__ esrc, const int* __restrict__ edst,
    float* __restrict__ hs1, float* __restrict__ hs2,
    float* __restrict__ out)
{
  extern __shared__ char smem[];
  float*          stageF = (float*)(smem + OFF_STAGE);
  float*          bufB  = (float*)(smem + OFF_BUFB);
  unsigned short* csr   = (unsigned short*)(smem + OFF_CSR);
  unsigned short* offs  = (unsigned short*)(smem + OFF_OFFS);
  unsigned int*   wt    = (unsigned int*)(smem + OFF_WT);
  unsigned int*   cur   = (unsigned int*)(smem + OFF_CUR);
  unsigned int*   dcnt  = (unsigned int*)(smem + OFF_DCNT);
  float*          nrm   = (float*)(smem + OFF_NRM);
  float*          lin3S = (float*)(smem + OFF_L3);
  float*          keyA  = (float*)(smem + OFF_KEY);
  unsigned int*   idxA  = (unsigned int*)(smem + OFF_IDX);

  const int g    = blockIdx.x;
  const int tid  = threadIdx.x;
  const int lane = tid & 63;
  const int wv   = __builtin_amdgcn_readfirstlane(tid >> 6);   // 0..15, wave-uniform
  const int half = __builtin_amdgcn_readfirstlane(tid >> 9);   // 0/1, wave-uniform
  const int v    = tid & 511;                                  // node
  const int nb   = g * NP;
  const size_t gb = (size_t)g * (NP * 32);

  // x chunk loaders: chunk kc = dims [kc*32, kc*32+32) for all 512 rows.
  // thread's 4 slices: row = (tid>>3) + it*128, grp = tid&7 (16 B within the 128 B chunk-row)
  const int ldRow0 = tid >> 3;
  const int ldGrp  = tid & 7;
  const int ldSwz  = (ldGrp ^ (ldRow0 & 7)) * 16;   // row&7 invariant under +128
  auto load_chunk = [&](int kc, float4* xr) {
    const float* base = x + (size_t)nb * FDIM + kc * 32 + ldGrp * 4;
#pragma unroll
    for (int it = 0; it < 4; it++)
      xr[it] = *(const float4*)(base + (size_t)(ldRow0 + it * 128) * FDIM);
  };
  auto store_chunk = [&](const float4* xr) {
#pragma unroll
    for (int it = 0; it < 4; it++)
      *(float4*)(smem + OFF_STAGE + (ldRow0 + it * 128) * 128 + ldSwz) = xr[it];
  };

  // issue chunk-0 x loads up front (latency hidden behind edge/CSR phases)
  float4 xa[4], xb[4];
  load_chunk(0, xa);

  // ---------- phase 0: zero counters ----------
  if (tid < 512) { cur[tid] = 0u; dcnt[tid] = 0u; }
  __syncthreads();

  // ---------- phase 1: edges via int4 (regs), packed deg counts ----------
  int es[8], ed[8];
  {
    const int eb = g * EPG;
    const int4* s4 = (const int4*)(esrc + eb);
    const int4* d4 = (const int4*)(edst + eb);
    const int4 sa = s4[tid], sb = s4[tid + 1024];
    const int4 da = d4[tid], db = d4[tid + 1024];
    es[0]=sa.x-nb; es[1]=sa.y-nb; es[2]=sa.z-nb; es[3]=sa.w-nb;
    es[4]=sb.x-nb; es[5]=sb.y-nb; es[6]=sb.z-nb; es[7]=sb.w-nb;
    ed[0]=da.x-nb; ed[1]=da.y-nb; ed[2]=da.z-nb; ed[3]=da.w-nb;
    ed[4]=db.x-nb; ed[5]=db.y-nb; ed[6]=db.z-nb; ed[7]=db.w-nb;
#pragma unroll
    for (int i = 0; i < 8; i++) {
      atomicAdd(&dcnt[es[i]], 1u);        // out-degree (low 16)
      atomicAdd(&dcnt[ed[i]], 65536u);    // in-degree  (high 16)
    }
  }
  __syncthreads();

  // ---------- phase 2: norm; wave-shuffle scan of in-degree -> offs ----------
  unsigned c_scan = 0;
  if (tid < 512) {
    const unsigned cw = dcnt[tid];
    nrm[tid] = 1.0f / (float)((cw & 0xFFFFu) + 1u);
    c_scan = cw >> 16;
    for (int d = 1; d < 64; d <<= 1) {
      const unsigned t = __shfl_up(c_scan, (unsigned)d, 64);
      if (lane >= d) c_scan += t;
    }
    if (lane == 63) wt[wv] = c_scan;
  }
  __syncthreads();
  if (tid < 512) {
    unsigned base = 0;
    for (int w = 0; w < wv; w++) base += wt[w];
    offs[tid + 1] = (unsigned short)(base + c_scan);
    if (tid == 0) offs[0] = 0;
  }
  __syncthreads();

  // ---------- phase 3: fill CSR (src bucketed by dst) ----------
#pragma unroll
  for (int i = 0; i < 8; i++) {
    const unsigned pos = (unsigned)offs[ed[i]] + atomicAdd(&cur[ed[i]], 1u);
    csr[pos] = (unsigned short)es[i];
  }
  // es/ed dead from here -> frees 16 VGPRs before lin0

  // ---------- phase 4: lin0 via LDS-staged x chunks, explicit ping-pong ----------
  float acc0[16];
#pragma unroll
  for (int c = 0; c < 16; c++) acc0[c] = b0[half * 16 + c];
  const char* rowp = smem + OFF_STAGE + v * 128;
  const int vswz = v & 7;
  auto compute_chunk = [&](int kc) {
#pragma unroll
    for (int jg = 0; jg < 8; jg++) {
      const float4 t = *(const float4*)(rowp + ((jg ^ vswz) * 16));
#pragma unroll
      for (int c = 0; c < 16; c++) {
        const float* wr = W0 + (size_t)(half * 16 + c) * FDIM + kc * 32 + jg * 4;
        acc0[c] = fmaf(t.x, wr[0], acc0[c]);
        acc0[c] = fmaf(t.y, wr[1], acc0[c]);
        acc0[c] = fmaf(t.z, wr[2], acc0[c]);
        acc0[c] = fmaf(t.w, wr[3], acc0[c]);
      }
    }
  };
  store_chunk(xa);            // stage region untouched by phases 0-3
  __syncthreads();
  load_chunk(1, xb);
  compute_chunk(0);
  __syncthreads();
  store_chunk(xb);
  __syncthreads();
  load_chunk(2, xa);
  compute_chunk(1);
  __syncthreads();
  store_chunk(xa);
  __syncthreads();
  load_chunk(3, xb);
  compute_chunk(2);
  __syncthreads();
  store_chunk(xb);
  __syncthreads();
  compute_chunk(3);
  {
    float4* br = (float4*)(bufB + v * STB + half * 16);
#pragma unroll
    for (int j = 0; j < 4; j++)
      br[j] = make_float4(acc0[j*4+0], acc0[j*4+1], acc0[j*4+2], acc0[j*4+3]);
  }
  __syncthreads();

  // aggregate own half (16 ch): h = tanh(nrm * (self + sum_neigh)); unroll-2 edge loop
  float h[16];
  auto do_agg = [&]() {
    float4 A0, A1, A2, A3;
    const float4* sr = (const float4*)(bufB + v * STB + half * 16);
    A0 = sr[0]; A1 = sr[1]; A2 = sr[2]; A3 = sr[3];
    const int e0 = offs[v], e1 = offs[v + 1];
    int e = e0;
    for (; e + 1 < e1; e += 2) {
      const int s0 = csr[e], s1 = csr[e + 1];
      const float4* rb0 = (const float4*)(bufB + s0 * STB + half * 16);
      const float4* rb1 = (const float4*)(bufB + s1 * STB + half * 16);
      const float4 p0 = rb0[0], p1 = rb0[1], p2 = rb0[2], p3 = rb0[3];
      const float4 q0 = rb1[0], q1 = rb1[1], q2 = rb1[2], q3 = rb1[3];
      A0.x += p0.x + q0.x; A0.y += p0.y + q0.y; A0.z += p0.z + q0.z; A0.w += p0.w + q0.w;
      A1.x += p1.x + q1.x; A1.y += p1.y + q1.y; A1.z += p1.z + q1.z; A1.w += p1.w + q1.w;
      A2.x += p2.x + q2.x; A2.y += p2.y + q2.y; A2.z += p2.z + q2.z; A2.w += p2.w + q2.w;
      A3.x += p3.x + q3.x; A3.y += p3.y + q3.y; A3.z += p3.z + q3.z; A3.w += p3.w + q3.w;
    }
    if (e < e1) {
      const int s = csr[e];
      const float4* rb = (const float4*)(bufB + s * STB + half * 16);
      const float4 r0 = rb[0], r1 = rb[1], r2 = rb[2], r3 = rb[3];
      A0.x += r0.x; A0.y += r0.y; A0.z += r0.z; A0.w += r0.w;
      A1.x += r1.x; A1.y += r1.y; A1.z += r1.z; A1.w += r1.w;
      A2.x += r2.x; A2.y += r2.y; A2.z += r2.z; A2.w += r2.w;
      A3.x += r3.x; A3.y += r3.y; A3.z += r3.z; A3.w += r3.w;
    }
    const float nv = nrm[v];
    h[0]=tanhf(A0.x*nv); h[1]=tanhf(A0.y*nv); h[2]=tanhf(A0.z*nv); h[3]=tanhf(A0.w*nv);
    h[4]=tanhf(A1.x*nv); h[5]=tanhf(A1.y*nv); h[6]=tanhf(A1.z*nv); h[7]=tanhf(A1.w*nv);
    h[8]=tanhf(A2.x*nv); h[9]=tanhf(A2.y*nv); h[10]=tanhf(A2.z*nv); h[11]=tanhf(A2.w*nv);
    h[12]=tanhf(A3.x*nv); h[13]=tanhf(A3.y*nv); h[14]=tanhf(A3.z*nv); h[15]=tanhf(A3.w*nv);
  };

  auto put_h = [&]() {
    float4* br = (float4*)(bufB + v * STB + half * 16);
#pragma unroll
    for (int j = 0; j < 4; j++)
      br[j] = make_float4(h[j*4+0], h[j*4+1], h[j*4+2], h[j*4+3]);
  };

  auto spill = [&](float* dst) {
#pragma unroll
    for (int c = 0; c < 16; c++)
      dst[gb + (size_t)(half * 16 + c) * 512 + v] = h[c];
  };

  auto do_lin = [&](const float* __restrict__ W, const float* __restrict__ b) {
    float hf[32];
    const float4* rr = (const float4*)(bufB + v * STB);
#pragma unroll
    for (int j = 0; j < 8; j++) {
      const float4 t = rr[j];
      hf[j*4+0]=t.x; hf[j*4+1]=t.y; hf[j*4+2]=t.z; hf[j*4+3]=t.w;
    }
    __syncthreads();   // all row reads done before rewrite
    float acc[16];
#pragma unroll
    for (int c = 0; c < 16; c++) {
      const int C = half * 16 + c;
      const float* wr = W + C * 32;
      float a = b[C];
#pragma unroll
      for (int j = 0; j < 32; j++) a = fmaf(hf[j], wr[j], a);
      acc[c] = a;
    }
    float4* br = (float4*)(bufB + v * STB + half * 16);
#pragma unroll
    for (int j = 0; j < 4; j++)
      br[j] = make_float4(acc[j*4+0], acc[j*4+1], acc[j*4+2], acc[j*4+3]);
    __syncthreads();   // rows complete
  };

  // ---------- layers ----------
  do_agg();            // h1
  __syncthreads();
  put_h(); spill(hs1);
  __syncthreads();
  do_lin(W1, b1);
  do_agg();            // h2
  __syncthreads();
  put_h(); spill(hs2);
  __syncthreads();
  do_lin(W2, b2);
  do_agg();            // h3
  __syncthreads();
  put_h();             // h3 stays in bufB
  __syncthreads();

  // ---------- layer 3 (1 ch, double acc — sort key) ----------
  if (tid < 512) {
    const float4* rr = (const float4*)(bufB + tid * STB);
    double a = (double)b3[0];
#pragma unroll
    for (int j = 0; j < 8; j++) {
      const float4 t = rr[j];
      a = fma((double)t.x, (double)W3[j*4+0], a);
      a = fma((double)t.y, (double)W3[j*4+1], a);
      a = fma((double)t.z, (double)W3[j*4+2], a);
      a = fma((double)t.w, (double)W3[j*4+3], a);
    }
    lin3S[tid] = (float)a;
  }
  __syncthreads();
  float h4 = 0.f;
  if (tid < 512) {
    double a = (double)lin3S[tid];
    const int e0 = offs[tid], e1 = offs[tid + 1];
    for (int e = e0; e < e1; e++) a += (double)lin3S[csr[e]];
    a *= (double)nrm[tid];
    h4 = tanhf((float)a);
  }
  __syncthreads();     // csr reads done; keyA/idxA may overlay csr

  // ---------- sort: in-wave bitonic (k=2..64, shfl, no barriers) ----------
  if (tid < 512) {
    float    sk = h4;
    unsigned si = (unsigned)tid;
#pragma unroll
    for (int kk = 2; kk <= 64; kk <<= 1) {
#pragma unroll
      for (int j = kk >> 1; j > 0; j >>= 1) {
        const float    pk = __shfl_xor(sk, j, 64);
        const unsigned pi = __shfl_xor(si, j, 64);
        const bool amFirst = (sk > pk) || (sk == pk && si < pi);
        const bool lower   = (lane & j) == 0;
        const bool dir     = (tid & kk) == 0;
        const bool keepMine = (lower == dir) ? amFirst : !amFirst;
        if (!keepMine) { sk = pk; si = pi; }
      }
    }
    keyA[tid] = sk;
    idxA[tid] = si;
  }
  // ---------- LDS bitonic stages k=128..512 ----------
  for (int k = 128; k <= NP; k <<= 1) {
    for (int j = k >> 1; j > 0; j >>= 1) {
      __syncthreads();
      if (tid < 512) {
        const int i = tid;
        const int l = i ^ j;
        if (l > i) {
          const float    ki = keyA[i], kl = keyA[l];
          const unsigned ii = idxA[i], il = idxA[l];
          const bool iBeforeL = (ki > kl) || (ki == kl && ii < il);
          const bool doSwap = ((i & k) == 0) ? (!iBeforeL) : iBeforeL;
          if (doSwap) {
            keyA[i] = kl; keyA[l] = ki;
            idxA[i] = il; idxA[l] = ii;
          }
        }
      }
    }
  }
  __syncthreads();

  // ---------- gather top-64 into featS [dim][node] (stage region, dead) ----------
  {
    float* featS = stageF + FO_FEAT;
    const int k = tid >> 4, t = tid & 15;   // 64 nodes x 16 threads
    const int node = (int)idxA[k];
#pragma unroll
    for (int m = 0; m < 7; m++) {
      const int d = t + 16 * m;
      float val;
      if (d < 32)       val = hs1[gb + (size_t)d * 512 + node];
      else if (d < 64)  val = hs2[gb + (size_t)(d - 32) * 512 + node];
      else if (d < 96)  val = bufB[node * STB + (d - 64)];
      else              val = keyA[k];
      if (d < 97) featS[d * 64 + k] = val;
    }
  }
  __syncthreads();

  // ---------- conv1 (per-node linear over 97), fp32: wave = 1 channel ----------
  {
    const float* featS = stageF + FO_FEAT;
    float* c1s = stageF + FO_C1;
    const int ch = wv;           // 0..15
    float a = c1b[ch];
    const float* wr = c1w + ch * 97;
    for (int d = 0; d < 97; d++)
      a = fmaf(featS[d * 64 + lane], wr[d], a);
    c1s[ch * 64 + lane] = fmaxf(a, 0.f);
  }
  __syncthreads();

  // ---------- maxpool(2,2) ----------
  if (tid < 512) {
    const float* c1s = stageF + FO_C1;
    float* ps  = stageF + FO_P;
    const int o = tid >> 5, jj = tid & 31;
    ps[o * 32 + jj] = fmaxf(c1s[o * 64 + 2 * jj], c1s[o * 64 + 2 * jj + 1]);
  }
  __syncthreads();

  // ---------- conv2 (k=5, valid), fp32: wave = 2 out channels ----------
  {
    const float* ps  = stageF + FO_P;
    float* c2s = stageF + FO_C2;
    const int o = wv;            // and o+16
    if (lane < 28) {
      float a0 = 0.f, a1 = 0.f;
      for (int i = 0; i < 16; i++) {
#pragma unroll
        for (int r = 0; r < 5; r++) {
          const float pv = ps[i * 32 + lane + r];
          a0 = fmaf(pv, c2w[((o     ) * 16 + i) * 5 + r], a0);
          a1 = fmaf(pv, c2w[((o + 16) * 16 + i) * 5 + r], a1);
        }
      }
      c2s[(o     ) * 28 + lane] = fmaxf(a0 + c2b[o     ], 0.f);
      c2s[(o + 16) * 28 + lane] = fmaxf(a1 + c2b[o + 16], 0.f);
    }
  }
  __syncthreads();

  // ---------- d1: 896 -> 128 relu, fp32; wave computes 8 outputs ----------
  {
    const float* c2s  = stageF + FO_C2;
    float* hids = stageF + FO_HID;
    float fl[14];
#pragma unroll
    for (int j = 0; j < 14; j++) fl[j] = c2s[lane + j * 64];
    for (int hh = 0; hh < 8; hh++) {
      const int hI = wv * 8 + hh;
      const float* wr = d1w + (size_t)hI * 896;
      float a = 0.f;
#pragma unroll
      for (int j = 0; j < 14; j++) a = fmaf(fl[j], wr[lane + j * 64], a);
#pragma unroll
      for (int m = 32; m > 0; m >>= 1) a += __shfl_xor(a, m, 64);
      if (lane == 0) hids[hI] = fmaxf(a + d1b[hI], 0.f);
    }
  }
  __syncthreads();

  // ---------- d2: 128 -> 10, fp32 ----------
  if (tid < 10) {
    const float* hids = stageF + FO_HID;
    const float* wr = d2w + tid * 128;
    float a = d2b[tid];
#pragma unroll 8
    for (int hh = 0; hh < 128; hh++) a = fmaf(hids[hh], wr[hh], a);
    out[g * 10 + tid] = a;
  }
}

extern "C" void kernel_launch(void* const* d_in, const int* in_sizes, int n_in,
                              void* d_out, int out_size, void* d_ws, size_t ws_size,
                              hipStream_t stream) {
  const float* x   = (const float*)d_in[0];
  const float* W0  = (const float*)d_in[1];
  const float* b0  = (const float*)d_in[2];
  const float* W1  = (const float*)d_in[3];
  const float* b1  = (const float*)d_in[4];
  const float* W2  = (const float*)d_in[5];
  const float* b2  = (const float*)d_in[6];
  const float* W3  = (const float*)d_in[7];
  const float* b3  = (const float*)d_in[8];
  const float* c1w = (const float*)d_in[9];
  const float* c1b = (const float*)d_in[10];
  const float* c2w = (const float*)d_in[11];
  const float* c2b = (const float*)d_in[12];
  const float* d1w = (const float*)d_in[13];
  const float* d1b = (const float*)d_in[14];
  const float* d2w = (const float*)d_in[15];
  const float* d2b = (const float*)d_in[16];
  const int* esrc  = (const int*)d_in[17];
  const int* edst  = (const int*)d_in[18];

  float* hs1 = (float*)d_ws;                       // 256*512*32 f32 = 16 MB
  float* hs2 = hs1 + (size_t)NG * NP * 32;         // +16 MB
  float* outp = (float*)d_out;

  hipFuncSetAttribute(reinterpret_cast<const void*>(dgcnn_fused),
                      hipFuncAttributeMaxDynamicSharedMemorySize, SMEM_SZ);
  dgcnn_fused<<<NG, 1024, SMEM_SZ, stream>>>(x, W0, b0, W1, b1, W2, b2, W3, b3,
                                             c1w, c1b, c2w, c2b, d1w, d1b, d2w, d2b,
                                             esrc, edst, hs1, hs2, outp);
}

// Round 6
// 288.901 us; speedup vs baseline: 1.7510x; 1.7510x over previous
//
#include <hip/hip_runtime.h>

#define NG   256   // graphs (= grid)
#define NP   512   // nodes per graph
#define EPG  8192  // edges per graph
#define FDIM 128
#define STB  36    // bufB stride (floats): 144 B, 16B-aligned; random-row starts spread 8 bank-groups

// ---- LDS layout (bytes) ----
#define OFF_STAGE 0                        // x chunk stage: 512 rows x 128 B = 65536
#define OFF_BUFB  65536                    // f32[512*36] = 73728 -> ends 139264
#define OFF_CSR   139264                   // u16[8192] = 16384 -> 155648
#define OFF_OFFS  155648                   // u16[513] -> 1032  -> 156680
#define OFF_WT    156680                   // u32[8] = 32       -> 156712
#define OFF_CUR   156712                   // u32[512] = 2048   -> 158760 (lin3S overlay later)
#define OFF_DCNT  158760                   // u32[512] = 2048   -> 160808
#define OFF_NRM   160808                   // f32[512] = 2048   -> 162856
#define SMEM_SZ   162856                   // <= 163840

// overlays
#define OFF_KEY  OFF_CSR                   // f32[512] (csr dead after layer-3 agg)
#define OFF_IDX  (OFF_CSR + 2048)          // u32[512]
#define OFF_L3   OFF_CUR                   // f32[512] (cursors dead after CSR build)
// tail arrays live in the dead stage region (float offsets from stage base)
#define FO_FEAT 0                          // f32[97*64] = 6208 floats
#define FO_C1   6208                       // f32[16*64]
#define FO_P    7232                       // f32[16*32]
#define FO_C2   7744                       // f32[896]
#define FO_HID  8640                       // f32[128]

__global__ __launch_bounds__(1024, 4) void dgcnn_fused(
    const float* __restrict__ x,
    const float* __restrict__ W0, const float* __restrict__ b0,
    const float* __restrict__ W1, const float* __restrict__ b1,
    const float* __restrict__ W2, const float* __restrict__ b2,
    const float* __restrict__ W3, const float* __restrict__ b3,
    const float* __restrict__ c1w, const float* __restrict__ c1b,
    const float* __restrict__ c2w, const float* __restrict__ c2b,
    const float* __restrict__ d1w, const float* __restrict__ d1b,
    const float* __restrict__ d2w, const float* __restrict__ d2b,
    const int* __restrict__ esrc, const int* __restrict__ edst,
    float* __restrict__ hs1, float* __restrict__ hs2,
    float* __restrict__ out)
{
  extern __shared__ char smem[];
  float*          stageF = (float*)(smem + OFF_STAGE);
  float*          bufB  = (float*)(smem + OFF_BUFB);
  unsigned short* csr   = (unsigned short*)(smem + OFF_CSR);
  unsigned short* offs  = (unsigned short*)(smem + OFF_OFFS);
  unsigned int*   wt    = (unsigned int*)(smem + OFF_WT);
  unsigned int*   cur   = (unsigned int*)(smem + OFF_CUR);
  unsigned int*   dcnt  = (unsigned int*)(smem + OFF_DCNT);
  float*          nrm   = (float*)(smem + OFF_NRM);
  float*          lin3S = (float*)(smem + OFF_L3);
  float*          keyA  = (float*)(smem + OFF_KEY);
  unsigned int*   idxA  = (unsigned int*)(smem + OFF_IDX);

  const int g    = blockIdx.x;
  const int tid  = threadIdx.x;
  const int lane = tid & 63;
  const int wv   = __builtin_amdgcn_readfirstlane(tid >> 6);   // 0..15, wave-uniform
  const int half = __builtin_amdgcn_readfirstlane(tid >> 9);   // 0/1, wave-uniform
  const int v    = tid & 511;                                  // node
  const int nb   = g * NP;
  const size_t gb = (size_t)g * (NP * 32);

  // x chunk staging: chunk kc = dims [kc*32, kc*32+32) for all 512 rows.
  // thread's 4 slices: row = (tid>>3) + it*128, grp = tid&7 (16 B within 128 B chunk-row)
  // ALL staging values in NAMED float4 registers (no local arrays -> no scratch!)
  const int ldRow0 = tid >> 3;
  const int ldGrp  = tid & 7;
  const int ldSwz  = (ldGrp ^ (ldRow0 & 7)) * 16;   // row&7 invariant under +128
  const float* xp0 = x + (size_t)nb * FDIM + ldGrp * 4 + (size_t)(ldRow0      ) * FDIM;
  const float* xp1 = x + (size_t)nb * FDIM + ldGrp * 4 + (size_t)(ldRow0 + 128) * FDIM;
  const float* xp2 = x + (size_t)nb * FDIM + ldGrp * 4 + (size_t)(ldRow0 + 256) * FDIM;
  const float* xp3 = x + (size_t)nb * FDIM + ldGrp * 4 + (size_t)(ldRow0 + 384) * FDIM;
  char* sp0 = smem + OFF_STAGE + (ldRow0      ) * 128 + ldSwz;
  char* sp1 = smem + OFF_STAGE + (ldRow0 + 128) * 128 + ldSwz;
  char* sp2 = smem + OFF_STAGE + (ldRow0 + 256) * 128 + ldSwz;
  char* sp3 = smem + OFF_STAGE + (ldRow0 + 384) * 128 + ldSwz;
#define LOADC(kc, r0, r1, r2, r3)                         \
  { r0 = *(const float4*)(xp0 + (kc) * 32);               \
    r1 = *(const float4*)(xp1 + (kc) * 32);               \
    r2 = *(const float4*)(xp2 + (kc) * 32);               \
    r3 = *(const float4*)(xp3 + (kc) * 32); }
#define STOREC(r0, r1, r2, r3)                            \
  { *(float4*)sp0 = r0; *(float4*)sp1 = r1;               \
    *(float4*)sp2 = r2; *(float4*)sp3 = r3; }

  float4 xA0, xA1, xA2, xA3, xB0, xB1, xB2, xB3;
  LOADC(0, xA0, xA1, xA2, xA3);   // issued before edge phases; latency hidden

  // ---------- phase 0: zero counters ----------
  if (tid < 512) { cur[tid] = 0u; dcnt[tid] = 0u; }
  __syncthreads();

  // ---------- phase 1: edges via int4 (regs), packed deg counts ----------
  int es[8], ed[8];
  {
    const int eb = g * EPG;
    const int4* s4 = (const int4*)(esrc + eb);
    const int4* d4 = (const int4*)(edst + eb);
    const int4 sa = s4[tid], sb = s4[tid + 1024];
    const int4 da = d4[tid], db = d4[tid + 1024];
    es[0]=sa.x-nb; es[1]=sa.y-nb; es[2]=sa.z-nb; es[3]=sa.w-nb;
    es[4]=sb.x-nb; es[5]=sb.y-nb; es[6]=sb.z-nb; es[7]=sb.w-nb;
    ed[0]=da.x-nb; ed[1]=da.y-nb; ed[2]=da.z-nb; ed[3]=da.w-nb;
    ed[4]=db.x-nb; ed[5]=db.y-nb; ed[6]=db.z-nb; ed[7]=db.w-nb;
#pragma unroll
    for (int i = 0; i < 8; i++) {
      atomicAdd(&dcnt[es[i]], 1u);        // out-degree (low 16)
      atomicAdd(&dcnt[ed[i]], 65536u);    // in-degree  (high 16)
    }
  }
  __syncthreads();

  // ---------- phase 2: norm; wave-shuffle scan of in-degree -> offs ----------
  unsigned c_scan = 0;
  if (tid < 512) {
    const unsigned cw = dcnt[tid];
    nrm[tid] = 1.0f / (float)((cw & 0xFFFFu) + 1u);
    c_scan = cw >> 16;
    for (int d = 1; d < 64; d <<= 1) {
      const unsigned t = __shfl_up(c_scan, (unsigned)d, 64);
      if (lane >= d) c_scan += t;
    }
    if (lane == 63) wt[wv] = c_scan;
  }
  __syncthreads();
  if (tid < 512) {
    unsigned base = 0;
    for (int w = 0; w < wv; w++) base += wt[w];
    offs[tid + 1] = (unsigned short)(base + c_scan);
    if (tid == 0) offs[0] = 0;
  }
  __syncthreads();

  // ---------- phase 3: fill CSR (src bucketed by dst) ----------
#pragma unroll
  for (int i = 0; i < 8; i++) {
    const unsigned pos = (unsigned)offs[ed[i]] + atomicAdd(&cur[ed[i]], 1u);
    csr[pos] = (unsigned short)es[i];
  }
  // es/ed dead from here

  // ---------- phase 4: lin0 via LDS-staged x chunks (register ping-pong) ----------
  float acc0[16];
#pragma unroll
  for (int c = 0; c < 16; c++) acc0[c] = b0[half * 16 + c];
  const char* rowp = smem + OFF_STAGE + v * 128;
  const int vswz = v & 7;
  auto compute_chunk = [&](int kc) {
#pragma unroll
    for (int jg = 0; jg < 8; jg++) {
      const float4 t = *(const float4*)(rowp + ((jg ^ vswz) * 16));
#pragma unroll
      for (int c = 0; c < 16; c++) {
        const float* wr = W0 + (size_t)(half * 16 + c) * FDIM + kc * 32 + jg * 4;
        acc0[c] = fmaf(t.x, wr[0], acc0[c]);
        acc0[c] = fmaf(t.y, wr[1], acc0[c]);
        acc0[c] = fmaf(t.z, wr[2], acc0[c]);
        acc0[c] = fmaf(t.w, wr[3], acc0[c]);
      }
    }
  };
  STOREC(xA0, xA1, xA2, xA3);   // stage untouched by phases 0-3
  LOADC(1, xB0, xB1, xB2, xB3);
  __syncthreads();
  compute_chunk(0);
  __syncthreads();
  STOREC(xB0, xB1, xB2, xB3);
  LOADC(2, xA0, xA1, xA2, xA3);
  __syncthreads();
  compute_chunk(1);
  __syncthreads();
  STOREC(xA0, xA1, xA2, xA3);
  LOADC(3, xB0, xB1, xB2, xB3);
  __syncthreads();
  compute_chunk(2);
  __syncthreads();
  STOREC(xB0, xB1, xB2, xB3);
  __syncthreads();
  compute_chunk(3);
  {
    float4* br = (float4*)(bufB + v * STB + half * 16);
#pragma unroll
    for (int j = 0; j < 4; j++)
      br[j] = make_float4(acc0[j*4+0], acc0[j*4+1], acc0[j*4+2], acc0[j*4+3]);
  }
  __syncthreads();

  // aggregate own half (16 ch): h = tanh(nrm * (self + sum_neigh)); unroll-2 edge loop
  float h[16];
  auto do_agg = [&]() {
    float4 A0, A1, A2, A3;
    const float4* sr = (const float4*)(bufB + v * STB + half * 16);
    A0 = sr[0]; A1 = sr[1]; A2 = sr[2]; A3 = sr[3];
    const int e0 = offs[v], e1 = offs[v + 1];
    int e = e0;
    for (; e + 1 < e1; e += 2) {
      const int s0 = csr[e], s1 = csr[e + 1];
      const float4* rb0 = (const float4*)(bufB + s0 * STB + half * 16);
      const float4* rb1 = (const float4*)(bufB + s1 * STB + half * 16);
      const float4 p0 = rb0[0], p1 = rb0[1], p2 = rb0[2], p3 = rb0[3];
      const float4 q0 = rb1[0], q1 = rb1[1], q2 = rb1[2], q3 = rb1[3];
      A0.x += p0.x + q0.x; A0.y += p0.y + q0.y; A0.z += p0.z + q0.z; A0.w += p0.w + q0.w;
      A1.x += p1.x + q1.x; A1.y += p1.y + q1.y; A1.z += p1.z + q1.z; A1.w += p1.w + q1.w;
      A2.x += p2.x + q2.x; A2.y += p2.y + q2.y; A2.z += p2.z + q2.z; A2.w += p2.w + q2.w;
      A3.x += p3.x + q3.x; A3.y += p3.y + q3.y; A3.z += p3.z + q3.z; A3.w += p3.w + q3.w;
    }
    if (e < e1) {
      const int s = csr[e];
      const float4* rb = (const float4*)(bufB + s * STB + half * 16);
      const float4 r0 = rb[0], r1 = rb[1], r2 = rb[2], r3 = rb[3];
      A0.x += r0.x; A0.y += r0.y; A0.z += r0.z; A0.w += r0.w;
      A1.x += r1.x; A1.y += r1.y; A1.z += r1.z; A1.w += r1.w;
      A2.x += r2.x; A2.y += r2.y; A2.z += r2.z; A2.w += r2.w;
      A3.x += r3.x; A3.y += r3.y; A3.z += r3.z; A3.w += r3.w;
    }
    const float nv = nrm[v];
    h[0]=tanhf(A0.x*nv); h[1]=tanhf(A0.y*nv); h[2]=tanhf(A0.z*nv); h[3]=tanhf(A0.w*nv);
    h[4]=tanhf(A1.x*nv); h[5]=tanhf(A1.y*nv); h[6]=tanhf(A1.z*nv); h[7]=tanhf(A1.w*nv);
    h[8]=tanhf(A2.x*nv); h[9]=tanhf(A2.y*nv); h[10]=tanhf(A2.z*nv); h[11]=tanhf(A2.w*nv);
    h[12]=tanhf(A3.x*nv); h[13]=tanhf(A3.y*nv); h[14]=tanhf(A3.z*nv); h[15]=tanhf(A3.w*nv);
  };

  auto put_h = [&]() {
    float4* br = (float4*)(bufB + v * STB + half * 16);
#pragma unroll
    for (int j = 0; j < 4; j++)
      br[j] = make_float4(h[j*4+0], h[j*4+1], h[j*4+2], h[j*4+3]);
  };

  auto spill = [&](float* dst) {
#pragma unroll
    for (int c = 0; c < 16; c++)
      dst[gb + (size_t)(half * 16 + c) * 512 + v] = h[c];
  };

  auto do_lin = [&](const float* __restrict__ W, const float* __restrict__ b) {
    float hf[32];
    const float4* rr = (const float4*)(bufB + v * STB);
#pragma unroll
    for (int j = 0; j < 8; j++) {
      const float4 t = rr[j];
      hf[j*4+0]=t.x; hf[j*4+1]=t.y; hf[j*4+2]=t.z; hf[j*4+3]=t.w;
    }
    __syncthreads();   // all row reads done before rewrite
    float acc[16];
#pragma unroll
    for (int c = 0; c < 16; c++) {
      const int C = half * 16 + c;
      const float* wr = W + C * 32;
      float a = b[C];
#pragma unroll
      for (int j = 0; j < 32; j++) a = fmaf(hf[j], wr[j], a);
      acc[c] = a;
    }
    float4* br = (float4*)(bufB + v * STB + half * 16);
#pragma unroll
    for (int j = 0; j < 4; j++)
      br[j] = make_float4(acc[j*4+0], acc[j*4+1], acc[j*4+2], acc[j*4+3]);
    __syncthreads();   // rows complete
  };

  // ---------- layers ----------
  do_agg();            // h1
  __syncthreads();
  put_h(); spill(hs1);
  __syncthreads();
  do_lin(W1, b1);
  do_agg();            // h2
  __syncthreads();
  put_h(); spill(hs2);
  __syncthreads();
  do_lin(W2, b2);
  do_agg();            // h3
  __syncthreads();
  put_h();             // h3 stays in bufB
  __syncthreads();

  // ---------- layer 3 (1 ch, double acc — sort key) ----------
  if (tid < 512) {
    const float4* rr = (const float4*)(bufB + tid * STB);
    double a = (double)b3[0];
#pragma unroll
    for (int j = 0; j < 8; j++) {
      const float4 t = rr[j];
      a = fma((double)t.x, (double)W3[j*4+0], a);
      a = fma((double)t.y, (double)W3[j*4+1], a);
      a = fma((double)t.z, (double)W3[j*4+2], a);
      a = fma((double)t.w, (double)W3[j*4+3], a);
    }
    lin3S[tid] = (float)a;
  }
  __syncthreads();
  float h4 = 0.f;
  if (tid < 512) {
    double a = (double)lin3S[tid];
    const int e0 = offs[tid], e1 = offs[tid + 1];
    for (int e = e0; e < e1; e++) a += (double)lin3S[csr[e]];
    a *= (double)nrm[tid];
    h4 = tanhf((float)a);
  }
  __syncthreads();     // csr reads done; keyA/idxA may overlay csr

  // ---------- sort: in-wave bitonic (k=2..64, shfl, no barriers) ----------
  if (tid < 512) {
    float    sk = h4;
    unsigned si = (unsigned)tid;
#pragma unroll
    for (int kk = 2; kk <= 64; kk <<= 1) {
#pragma unroll
      for (int j = kk >> 1; j > 0; j >>= 1) {
        const float    pk = __shfl_xor(sk, j, 64);
        const unsigned pi = __shfl_xor(si, j, 64);
        const bool amFirst = (sk > pk) || (sk == pk && si < pi);
        const bool lower   = (lane & j) == 0;
        const bool dir     = (tid & kk) == 0;
        const bool keepMine = (lower == dir) ? amFirst : !amFirst;
        if (!keepMine) { sk = pk; si = pi; }
      }
    }
    keyA[tid] = sk;
    idxA[tid] = si;
  }
  // ---------- LDS bitonic stages k=128..512 ----------
  for (int k = 128; k <= NP; k <<= 1) {
    for (int j = k >> 1; j > 0; j >>= 1) {
      __syncthreads();
      if (tid < 512) {
        const int i = tid;
        const int l = i ^ j;
        if (l > i) {
          const float    ki = keyA[i], kl = keyA[l];
          const unsigned ii = idxA[i], il = idxA[l];
          const bool iBeforeL = (ki > kl) || (ki == kl && ii < il);
          const bool doSwap = ((i & k) == 0) ? (!iBeforeL) : iBeforeL;
          if (doSwap) {
            keyA[i] = kl; keyA[l] = ki;
            idxA[i] = il; idxA[l] = ii;
          }
        }
      }
    }
  }
  __syncthreads();

  // ---------- gather top-64 into featS [dim][node] (stage region, dead) ----------
  {
    float* featS = stageF + FO_FEAT;
    const int k = tid >> 4, t = tid & 15;   // 64 nodes x 16 threads
    const int node = (int)idxA[k];
#pragma unroll
    for (int m = 0; m < 7; m++) {
      const int d = t + 16 * m;
      float val;
      if (d < 32)       val = hs1[gb + (size_t)d * 512 + node];
      else if (d < 64)  val = hs2[gb + (size_t)(d - 32) * 512 + node];
      else if (d < 96)  val = bufB[node * STB + (d - 64)];
      else              val = keyA[k];
      if (d < 97) featS[d * 64 + k] = val;
    }
  }
  __syncthreads();

  // ---------- conv1 (per-node linear over 97), fp32: wave = 1 channel ----------
  {
    const float* featS = stageF + FO_FEAT;
    float* c1s = stageF + FO_C1;
    const int ch = wv;           // 0..15
    float a = c1b[ch];
    const float* wr = c1w + ch * 97;
    for (int d = 0; d < 97; d++)
      a = fmaf(featS[d * 64 + lane], wr[d], a);
    c1s[ch * 64 + lane] = fmaxf(a, 0.f);
  }
  __syncthreads();

  // ---------- maxpool(2,2) ----------
  if (tid < 512) {
    const float* c1s = stageF + FO_C1;
    float* ps  = stageF + FO_P;
    const int o = tid >> 5, jj = tid & 31;
    ps[o * 32 + jj] = fmaxf(c1s[o * 64 + 2 * jj], c1s[o * 64 + 2 * jj + 1]);
  }
  __syncthreads();

  // ---------- conv2 (k=5, valid), fp32: wave = 2 out channels ----------
  {
    const float* ps  = stageF + FO_P;
    float* c2s = stageF + FO_C2;
    const int o = wv;            // and o+16
    if (lane < 28) {
      float a0 = 0.f, a1 = 0.f;
      for (int i = 0; i < 16; i++) {
#pragma unroll
        for (int r = 0; r < 5; r++) {
          const float pv = ps[i * 32 + lane + r];
          a0 = fmaf(pv, c2w[((o     ) * 16 + i) * 5 + r], a0);
          a1 = fmaf(pv, c2w[((o + 16) * 16 + i) * 5 + r], a1);
        }
      }
      c2s[(o     ) * 28 + lane] = fmaxf(a0 + c2b[o     ], 0.f);
      c2s[(o + 16) * 28 + lane] = fmaxf(a1 + c2b[o + 16], 0.f);
    }
  }
  __syncthreads();

  // ---------- d1: 896 -> 128 relu, fp32; wave computes 8 outputs ----------
  {
    const float* c2s  = stageF + FO_C2;
    float* hids = stageF + FO_HID;
    float fl[14];
#pragma unroll
    for (int j = 0; j < 14; j++) fl[j] = c2s[lane + j * 64];
    for (int hh = 0; hh < 8; hh++) {
      const int hI = wv * 8 + hh;
      const float* wr = d1w + (size_t)hI * 896;
      float a = 0.f;
#pragma unroll
      for (int j = 0; j < 14; j++) a = fmaf(fl[j], wr[lane + j * 64], a);
#pragma unroll
      for (int m = 32; m > 0; m >>= 1) a += __shfl_xor(a, m, 64);
      if (lane == 0) hids[hI] = fmaxf(a + d1b[hI], 0.f);
    }
  }
  __syncthreads();

  // ---------- d2: 128 -> 10, fp32 ----------
  if (tid < 10) {
    const float* hids = stageF + FO_HID;
    const float* wr = d2w + tid * 128;
    float a = d2b[tid];
#pragma unroll 8
    for (int hh = 0; hh < 128; hh++) a = fmaf(hids[hh], wr[hh], a);
    out[g * 10 + tid] = a;
  }
}

extern "C" void kernel_launch(void* const* d_in, const int* in_sizes, int n_in,
                              void* d_out, int out_size, void* d_ws, size_t ws_size,
                              hipStream_t stream) {
  const float* x   = (const float*)d_in[0];
  const float* W0  = (const float*)d_in[1];
  const float* b0  = (const float*)d_in[2];
  const float* W1  = (const float*)d_in[3];
  const float* b1  = (const float*)d_in[4];
  const float* W2  = (const float*)d_in[5];
  const float* b2  = (const float*)d_in[6];
  const float* W3  = (const float*)d_in[7];
  const float* b3  = (const float*)d_in[8];
  const float* c1w = (const float*)d_in[9];
  const float* c1b = (const float*)d_in[10];
  const float* c2w = (const float*)d_in[11];
  const float* c2b = (const float*)d_in[12];
  const float* d1w = (const float*)d_in[13];
  const float* d1b = (const float*)d_in[14];
  const float* d2w = (const float*)d_in[15];
  const float* d2b = (const float*)d_in[16];
  const int* esrc  = (const int*)d_in[17];
  const int* edst  = (const int*)d_in[18];

  float* hs1 = (float*)d_ws;                       // 256*512*32 f32 = 16 MB
  float* hs2 = hs1 + (size_t)NG * NP * 32;         // +16 MB
  float* outp = (float*)d_out;

  hipFuncSetAttribute(reinterpret_cast<const void*>(dgcnn_fused),
                      hipFuncAttributeMaxDynamicSharedMemorySize, SMEM_SZ);
  dgcnn_fused<<<NG, 1024, SMEM_SZ, stream>>>(x, W0, b0, W1, b1, W2, b2, W3, b3,
                                             c1w, c1b, c2w, c2b, d1w, d1b, d2w, d2b,
                                             esrc, edst, hs1, hs2, outp);
}

// Round 7
// 286.972 us; speedup vs baseline: 1.7628x; 1.0067x over previous
//
#include <hip/hip_runtime.h>

#define NG   256   // graphs (= grid)
#define NP   512   // nodes per graph
#define EPG  8192  // edges per graph
#define FDIM 128
#define STA  33    // bufA stride (floats): 4-B rotation -> conflict-free b32 row access
#define STB  36    // bufB stride (floats): 144 B, 16B-aligned; random-row b128 spread 8 bank-groups

// ---- LDS layout (bytes) ----
#define OFF_BUFA  0                        // max(stage 512*128=65536, bufA 512*33*4=67584) = 67584
#define OFF_BUFB  67584                    // f32[512*36] = 73728 -> 141312
#define OFF_CSR   141312                   // u16[8192] = 16384 -> 157696
#define OFF_OFFS  157696                   // u16[513] -> 1032 -> 158728
#define OFF_WT    158728                   // u32[8] = 32 -> 158760
#define OFF_DCNT  158760                   // u32[512] = 2048 -> 160808 (deg counts, then cursors, then lin3S)
#define OFF_NRM   160808                   // f32[512] = 2048 -> 162856
#define SMEM_SZ   162856                   // <= 163840

// overlays in csr region (dead after key aggregation)
#define OFF_KEYA OFF_CSR                   // f32[512]
#define OFF_IDXA (OFF_CSR + 2048)         // u32[512]
#define OFF_KEYB (OFF_CSR + 4096)         // f32[256] (merge ping-pong)
#define OFF_IDXB (OFF_CSR + 6144)         // u32[256]
// tail arrays in bufA/stage region (float offsets)
#define FO_FEAT 0                          // f32[97*64]
#define FO_C1   6208                       // f32[16*64]
#define FO_P    7232                       // f32[16*32]
#define FO_C2   7744                       // f32[896]
#define FO_HID  8640                       // f32[128]

__global__ __launch_bounds__(1024, 4) void dgcnn_fused(
    const float* __restrict__ x,
    const float* __restrict__ W0, const float* __restrict__ b0,
    const float* __restrict__ W1, const float* __restrict__ b1,
    const float* __restrict__ W2, const float* __restrict__ b2,
    const float* __restrict__ W3, const float* __restrict__ b3,
    const float* __restrict__ c1w, const float* __restrict__ c1b,
    const float* __restrict__ c2w, const float* __restrict__ c2b,
    const float* __restrict__ d1w, const float* __restrict__ d1b,
    const float* __restrict__ d2w, const float* __restrict__ d2b,
    const int* __restrict__ esrc, const int* __restrict__ edst,
    float* __restrict__ hs1, float* __restrict__ hs2,
    float* __restrict__ out)
{
  extern __shared__ char smem[];
  float*          stageF = (float*)(smem + OFF_BUFA);
  float*          bufA  = (float*)(smem + OFF_BUFA);
  float*          bufB  = (float*)(smem + OFF_BUFB);
  unsigned short* csr   = (unsigned short*)(smem + OFF_CSR);
  unsigned short* offs  = (unsigned short*)(smem + OFF_OFFS);
  unsigned int*   wt    = (unsigned int*)(smem + OFF_WT);
  unsigned int*   dcnt  = (unsigned int*)(smem + OFF_DCNT);  // also cursors, then lin3S
  float*          nrm   = (float*)(smem + OFF_NRM);
  float*          lin3S = (float*)(smem + OFF_DCNT);
  float*          keyA  = (float*)(smem + OFF_KEYA);
  unsigned int*   idxA  = (unsigned int*)(smem + OFF_IDXA);
  float*          keyB  = (float*)(smem + OFF_KEYB);
  unsigned int*   idxB  = (unsigned int*)(smem + OFF_IDXB);

  const int g    = blockIdx.x;
  const int tid  = threadIdx.x;
  const int lane = tid & 63;
  const int wv   = __builtin_amdgcn_readfirstlane(tid >> 6);   // 0..15, wave-uniform
  const int half = __builtin_amdgcn_readfirstlane(tid >> 9);   // 0/1, wave-uniform
  const int v    = tid & 511;                                  // node
  const int nb   = g * NP;
  const size_t gb = (size_t)g * (NP * 32);

  // x chunk staging (named regs only -> no scratch)
  const int ldRow0 = tid >> 3;
  const int ldGrp  = tid & 7;
  const int ldSwz  = (ldGrp ^ (ldRow0 & 7)) * 16;
  const float* xp0 = x + (size_t)nb * FDIM + ldGrp * 4 + (size_t)(ldRow0      ) * FDIM;
  const float* xp1 = x + (size_t)nb * FDIM + ldGrp * 4 + (size_t)(ldRow0 + 128) * FDIM;
  const float* xp2 = x + (size_t)nb * FDIM + ldGrp * 4 + (size_t)(ldRow0 + 256) * FDIM;
  const float* xp3 = x + (size_t)nb * FDIM + ldGrp * 4 + (size_t)(ldRow0 + 384) * FDIM;
  char* sp0 = smem + OFF_BUFA + (ldRow0      ) * 128 + ldSwz;
  char* sp1 = smem + OFF_BUFA + (ldRow0 + 128) * 128 + ldSwz;
  char* sp2 = smem + OFF_BUFA + (ldRow0 + 256) * 128 + ldSwz;
  char* sp3 = smem + OFF_BUFA + (ldRow0 + 384) * 128 + ldSwz;
#define LOADC(kc, r0, r1, r2, r3)                         \
  { r0 = *(const float4*)(xp0 + (kc) * 32);               \
    r1 = *(const float4*)(xp1 + (kc) * 32);               \
    r2 = *(const float4*)(xp2 + (kc) * 32);               \
    r3 = *(const float4*)(xp3 + (kc) * 32); }
#define STOREC(r0, r1, r2, r3)                            \
  { *(float4*)sp0 = r0; *(float4*)sp1 = r1;               \
    *(float4*)sp2 = r2; *(float4*)sp3 = r3; }

  float4 xA0, xA1, xA2, xA3, xB0, xB1, xB2, xB3;
  LOADC(0, xA0, xA1, xA2, xA3);

  // ---------- phase 0: zero deg counters ----------
  if (tid < 512) dcnt[tid] = 0u;
  __syncthreads();

  // ---------- phase 1: edges via int4, packed deg counts ----------
  int es[8], ed[8];
  {
    const int eb = g * EPG;
    const int4* s4 = (const int4*)(esrc + eb);
    const int4* d4 = (const int4*)(edst + eb);
    const int4 sa = s4[tid], sb = s4[tid + 1024];
    const int4 da = d4[tid], db = d4[tid + 1024];
    es[0]=sa.x-nb; es[1]=sa.y-nb; es[2]=sa.z-nb; es[3]=sa.w-nb;
    es[4]=sb.x-nb; es[5]=sb.y-nb; es[6]=sb.z-nb; es[7]=sb.w-nb;
    ed[0]=da.x-nb; ed[1]=da.y-nb; ed[2]=da.z-nb; ed[3]=da.w-nb;
    ed[4]=db.x-nb; ed[5]=db.y-nb; ed[6]=db.z-nb; ed[7]=db.w-nb;
#pragma unroll
    for (int i = 0; i < 8; i++) {
      atomicAdd(&dcnt[es[i]], 1u);        // out-degree (low 16)
      atomicAdd(&dcnt[ed[i]], 65536u);    // in-degree  (high 16)
    }
  }
  __syncthreads();

  // ---------- phase 2: norm; wave scan of in-degree -> offs; re-zero as cursors ----------
  unsigned c_scan = 0;
  if (tid < 512) {
    const unsigned cw = dcnt[tid];
    nrm[tid] = 1.0f / (float)((cw & 0xFFFFu) + 1u);
    dcnt[tid] = 0u;                       // own element read; becomes cursor
    c_scan = cw >> 16;
    for (int d = 1; d < 64; d <<= 1) {
      const unsigned t = __shfl_up(c_scan, (unsigned)d, 64);
      if (lane >= d) c_scan += t;
    }
    if (lane == 63) wt[wv] = c_scan;
  }
  __syncthreads();
  if (tid < 512) {
    unsigned base = 0;
    for (int w = 0; w < wv; w++) base += wt[w];
    offs[tid + 1] = (unsigned short)(base + c_scan);
    if (tid == 0) offs[0] = 0;
  }
  __syncthreads();

  // ---------- phase 3: fill CSR (src bucketed by dst) ----------
#pragma unroll
  for (int i = 0; i < 8; i++) {
    const unsigned pos = (unsigned)offs[ed[i]] + atomicAdd(&dcnt[ed[i]], 1u);
    csr[pos] = (unsigned short)es[i];
  }

  // ---------- phase 4: lin0 via LDS-staged x chunks ----------
  float acc0[16];
#pragma unroll
  for (int c = 0; c < 16; c++) acc0[c] = b0[half * 16 + c];
  const char* rowp = smem + OFF_BUFA + v * 128;
  const int vswz = v & 7;
  auto compute_chunk = [&](int kc) {
#pragma unroll
    for (int jg = 0; jg < 8; jg++) {
      const float4 t = *(const float4*)(rowp + ((jg ^ vswz) * 16));
#pragma unroll
      for (int c = 0; c < 16; c++) {
        const float* wr = W0 + (size_t)(half * 16 + c) * FDIM + kc * 32 + jg * 4;
        acc0[c] = fmaf(t.x, wr[0], acc0[c]);
        acc0[c] = fmaf(t.y, wr[1], acc0[c]);
        acc0[c] = fmaf(t.z, wr[2], acc0[c]);
        acc0[c] = fmaf(t.w, wr[3], acc0[c]);
      }
    }
  };
  STOREC(xA0, xA1, xA2, xA3);
  LOADC(1, xB0, xB1, xB2, xB3);
  __syncthreads();
  compute_chunk(0);
  __syncthreads();
  STOREC(xB0, xB1, xB2, xB3);
  LOADC(2, xA0, xA1, xA2, xA3);
  __syncthreads();
  compute_chunk(1);
  __syncthreads();
  STOREC(xA0, xA1, xA2, xA3);
  LOADC(3, xB0, xB1, xB2, xB3);
  __syncthreads();
  compute_chunk(2);
  __syncthreads();
  STOREC(xB0, xB1, xB2, xB3);
  __syncthreads();
  compute_chunk(3);
  {
    float4* br = (float4*)(bufB + v * STB + half * 16);
#pragma unroll
    for (int j = 0; j < 4; j++)
      br[j] = make_float4(acc0[j*4+0], acc0[j*4+1], acc0[j*4+2], acc0[j*4+3]);
  }
  __syncthreads();

  // aggregate own half (16 ch) from bufB: h = tanh(nrm * (self + sum_neigh))
  float h[16];
  auto do_agg = [&]() {
    float4 A0, A1, A2, A3;
    const float4* sr = (const float4*)(bufB + v * STB + half * 16);
    A0 = sr[0]; A1 = sr[1]; A2 = sr[2]; A3 = sr[3];
    const int e0 = offs[v], e1 = offs[v + 1];
    int e = e0;
    for (; e + 1 < e1; e += 2) {
      const int s0 = csr[e], s1 = csr[e + 1];
      const float4* rb0 = (const float4*)(bufB + s0 * STB + half * 16);
      const float4* rb1 = (const float4*)(bufB + s1 * STB + half * 16);
      const float4 p0 = rb0[0], p1 = rb0[1], p2 = rb0[2], p3 = rb0[3];
      const float4 q0 = rb1[0], q1 = rb1[1], q2 = rb1[2], q3 = rb1[3];
      A0.x += p0.x + q0.x; A0.y += p0.y + q0.y; A0.z += p0.z + q0.z; A0.w += p0.w + q0.w;
      A1.x += p1.x + q1.x; A1.y += p1.y + q1.y; A1.z += p1.z + q1.z; A1.w += p1.w + q1.w;
      A2.x += p2.x + q2.x; A2.y += p2.y + q2.y; A2.z += p2.z + q2.z; A2.w += p2.w + q2.w;
      A3.x += p3.x + q3.x; A3.y += p3.y + q3.y; A3.z += p3.z + q3.z; A3.w += p3.w + q3.w;
    }
    if (e < e1) {
      const int s = csr[e];
      const float4* rb = (const float4*)(bufB + s * STB + half * 16);
      const float4 r0 = rb[0], r1 = rb[1], r2 = rb[2], r3 = rb[3];
      A0.x += r0.x; A0.y += r0.y; A0.z += r0.z; A0.w += r0.w;
      A1.x += r1.x; A1.y += r1.y; A1.z += r1.z; A1.w += r1.w;
      A2.x += r2.x; A2.y += r2.y; A2.z += r2.z; A2.w += r2.w;
      A3.x += r3.x; A3.y += r3.y; A3.z += r3.z; A3.w += r3.w;
    }
    const float nv = nrm[v];
    h[0]=tanhf(A0.x*nv); h[1]=tanhf(A0.y*nv); h[2]=tanhf(A0.z*nv); h[3]=tanhf(A0.w*nv);
    h[4]=tanhf(A1.x*nv); h[5]=tanhf(A1.y*nv); h[6]=tanhf(A1.z*nv); h[7]=tanhf(A1.w*nv);
    h[8]=tanhf(A2.x*nv); h[9]=tanhf(A2.y*nv); h[10]=tanhf(A2.z*nv); h[11]=tanhf(A2.w*nv);
    h[12]=tanhf(A3.x*nv); h[13]=tanhf(A3.y*nv); h[14]=tanhf(A3.z*nv); h[15]=tanhf(A3.w*nv);
  };

  // write own half of h into bufA (conflict-free b32s, stride 33)
  auto put_hA = [&]() {
    float* aw = bufA + v * STA + half * 16;
#pragma unroll
    for (int j = 0; j < 16; j++) aw[j] = h[j];
  };

  auto spill = [&](float* dst) {
#pragma unroll
    for (int c = 0; c < 16; c++)
      dst[gb + (size_t)(half * 16 + c) * 512 + v] = h[c];
  };

  // lin: own half from regs + other half from bufA -> bufB own row
  auto do_lin = [&](const float* __restrict__ W, const float* __restrict__ b) {
    float hf[16];
    const float* ar = bufA + v * STA + (half ^ 1) * 16;
#pragma unroll
    for (int j = 0; j < 16; j++) hf[j] = ar[j];
    float acc[16];
#pragma unroll
    for (int c = 0; c < 16; c++) {
      const int C = half * 16 + c;
      const float* wr = W + C * 32;
      float a = b[C];
#pragma unroll
      for (int j = 0; j < 16; j++) a = fmaf(h[j],  wr[half * 16 + j], a);
#pragma unroll
      for (int j = 0; j < 16; j++) a = fmaf(hf[j], wr[(half ^ 1) * 16 + j], a);
      acc[c] = a;
    }
    float4* br = (float4*)(bufB + v * STB + half * 16);
#pragma unroll
    for (int j = 0; j < 4; j++)
      br[j] = make_float4(acc[j*4+0], acc[j*4+1], acc[j*4+2], acc[j*4+3]);
  };

  // ---------- layers: 2 barriers each ----------
  do_agg();                       // h1 (reads bufB)
  put_hA(); spill(hs1);           // writes bufA (disjoint from bufB)
  __syncthreads();
  do_lin(W1, b1);                 // reads bufA, writes bufB
  __syncthreads();
  do_agg();                       // h2
  put_hA(); spill(hs2);
  __syncthreads();
  do_lin(W2, b2);
  __syncthreads();
  do_agg();                       // h3
  put_hA();                       // full h3 row lands in bufA
  __syncthreads();

  // ---------- layer 3 (1 ch, double acc — sort key) ----------
  if (tid < 512) {
    const float* ar = bufA + tid * STA;
    double a = (double)b3[0];
#pragma unroll
    for (int j = 0; j < 32; j++) a = fma((double)ar[j], (double)W3[j], a);
    lin3S[tid] = (float)a;
  }
  __syncthreads();
  float h4 = 0.f;
  if (tid < 512) {
    double a = (double)lin3S[tid];
    const int e0 = offs[tid], e1 = offs[tid + 1];
    for (int e = e0; e < e1; e++) a += (double)lin3S[csr[e]];
    a *= (double)nrm[tid];
    h4 = tanhf((float)a);
  }
  __syncthreads();     // csr reads done; keyA/idxA/keyB/idxB may overlay csr

  // ---------- in-wave bitonic sort (desc, stable) -> 8 sorted 64-lists ----------
  if (tid < 512) {
    float    sk = h4;
    unsigned si = (unsigned)tid;
#pragma unroll
    for (int kk = 2; kk <= 64; kk <<= 1) {
#pragma unroll
      for (int j = kk >> 1; j > 0; j >>= 1) {
        const float    pk = __shfl_xor(sk, j, 64);
        const unsigned pi = __shfl_xor(si, j, 64);
        const bool amFirst = (sk > pk) || (sk == pk && si < pi);
        const bool lower   = (lane & j) == 0;
        const bool dir     = (lane & kk) == 0;   // all-desc at kk=64
        const bool keepMine = (lower == dir) ? amFirst : !amFirst;
        if (!keepMine) { sk = pk; si = pi; }
      }
    }
    keyA[tid] = sk;
    idxA[tid] = si;
  }
  __syncthreads();

  // ---------- 3-round pairwise top-64 merge (wave-local, 1 barrier/round) ----------
  auto merge_round = [&](const float* kin, const unsigned* iin,
                         float* kout, unsigned* iout, int L, int R, int O) {
    float    ak = kin[L * 64 + lane];
    unsigned ai = iin[L * 64 + lane];
    float    bk = kin[R * 64 + 63 - lane];
    unsigned bi = iin[R * 64 + 63 - lane];
    float mk; unsigned mi;
    if ((ak > bk) || (ak == bk && ai < bi)) { mk = ak; mi = ai; }
    else                                    { mk = bk; mi = bi; }
#pragma unroll
    for (int j = 32; j > 0; j >>= 1) {
      const float    pk = __shfl_xor(mk, j, 64);
      const unsigned pi = __shfl_xor(mi, j, 64);
      const bool amF   = (mk > pk) || (mk == pk && mi < pi);
      const bool lower = (lane & j) == 0;
      if (lower != amF) { mk = pk; mi = pi; }
    }
    kout[O * 64 + lane] = mk;
    iout[O * 64 + lane] = mi;
  };
  if (wv < 4) merge_round(keyA, idxA, keyB, idxB, 2 * wv, 2 * wv + 1, wv);
  __syncthreads();
  if (wv < 2) merge_round(keyB, idxB, keyA, idxA, 2 * wv, 2 * wv + 1, wv);
  __syncthreads();
  if (wv == 0) merge_round(keyA, idxA, keyB, idxB, 0, 1, 0);
  __syncthreads();
  // top-64 desc now in keyB/idxB[0..63]

  // ---------- gather top-64 into featS [dim][node] (overlays bufA!) ----------
  {
    float* featS = stageF + FO_FEAT;
    const int k = tid >> 4, t = tid & 15;   // 64 nodes x 16 threads
    const int node = (int)idxB[k];
    float vals[7];
#pragma unroll
    for (int m = 0; m < 7; m++) {
      const int d = t + 16 * m;
      float val = 0.f;
      if (d < 32)       val = hs1[gb + (size_t)d * 512 + node];
      else if (d < 64)  val = hs2[gb + (size_t)(d - 32) * 512 + node];
      else if (d < 96)  val = bufA[node * STA + (d - 64)];
      else              val = keyB[k];
      vals[m] = val;
    }
    __syncthreads();   // all bufA(h3) reads done before featS overlay writes
#pragma unroll
    for (int m = 0; m < 7; m++) {
      const int d = t + 16 * m;
      if (d < 97) featS[d * 64 + k] = vals[m];
    }
  }
  __syncthreads();

  // ---------- conv1 (per-node linear over 97), fp32: wave = 1 channel ----------
  {
    const float* featS = stageF + FO_FEAT;
    float* c1s = stageF + FO_C1;
    const int ch = wv;           // 0..15
    float a = c1b[ch];
    const float* wr = c1w + ch * 97;
    for (int d = 0; d < 97; d++)
      a = fmaf(featS[d * 64 + lane], wr[d], a);
    c1s[ch * 64 + lane] = fmaxf(a, 0.f);
  }
  __syncthreads();

  // ---------- maxpool(2,2) ----------
  if (tid < 512) {
    const float* c1s = stageF + FO_C1;
    float* ps  = stageF + FO_P;
    const int o = tid >> 5, jj = tid & 31;
    ps[o * 32 + jj] = fmaxf(c1s[o * 64 + 2 * jj], c1s[o * 64 + 2 * jj + 1]);
  }
  __syncthreads();

  // ---------- conv2 (k=5, valid), fp32: wave = 2 out channels ----------
  {
    const float* ps  = stageF + FO_P;
    float* c2s = stageF + FO_C2;
    const int o = wv;            // and o+16
    if (lane < 28) {
      float a0 = 0.f, a1 = 0.f;
      for (int i = 0; i < 16; i++) {
#pragma unroll
        for (int r = 0; r < 5; r++) {
          const float pv = ps[i * 32 + lane + r];
          a0 = fmaf(pv, c2w[((o     ) * 16 + i) * 5 + r], a0);
          a1 = fmaf(pv, c2w[((o + 16) * 16 + i) * 5 + r], a1);
        }
      }
      c2s[(o     ) * 28 + lane] = fmaxf(a0 + c2b[o     ], 0.f);
      c2s[(o + 16) * 28 + lane] = fmaxf(a1 + c2b[o + 16], 0.f);
    }
  }
  __syncthreads();

  // ---------- d1: 896 -> 128 relu, fp32; wave computes 8 outputs ----------
  {
    const float* c2s  = stageF + FO_C2;
    float* hids = stageF + FO_HID;
    float fl[14];
#pragma unroll
    for (int j = 0; j < 14; j++) fl[j] = c2s[lane + j * 64];
    for (int hh = 0; hh < 8; hh++) {
      const int hI = wv * 8 + hh;
      const float* wr = d1w + (size_t)hI * 896;
      float a = 0.f;
#pragma unroll
      for (int j = 0; j < 14; j++) a = fmaf(fl[j], wr[lane + j * 64], a);
#pragma unroll
      for (int m = 32; m > 0; m >>= 1) a += __shfl_xor(a, m, 64);
      if (lane == 0) hids[hI] = fmaxf(a + d1b[hI], 0.f);
    }
  }
  __syncthreads();

  // ---------- d2: 128 -> 10, fp32 ----------
  if (tid < 10) {
    const float* hids = stageF + FO_HID;
    const float* wr = d2w + tid * 128;
    float a = d2b[tid];
#pragma unroll 8
    for (int hh = 0; hh < 128; hh++) a = fmaf(hids[hh], wr[hh], a);
    out[g * 10 + tid] = a;
  }
}

extern "C" void kernel_launch(void* const* d_in, const int* in_sizes, int n_in,
                              void* d_out, int out_size, void* d_ws, size_t ws_size,
                              hipStream_t stream) {
  const float* x   = (const float*)d_in[0];
  const float* W0  = (const float*)d_in[1];
  const float* b0  = (const float*)d_in[2];
  const float* W1  = (const float*)d_in[3];
  const float* b1  = (const float*)d_in[4];
  const float* W2  = (const float*)d_in[5];
  const float* b2  = (const float*)d_in[6];
  const float* W3  = (const float*)d_in[7];
  const float* b3  = (const float*)d_in[8];
  const float* c1w = (const float*)d_in[9];
  const float* c1b = (const float*)d_in[10];
  const float* c2w = (const float*)d_in[11];
  const float* c2b = (const float*)d_in[12];
  const float* d1w = (const float*)d_in[13];
  const float* d1b = (const float*)d_in[14];
  const float* d2w = (const float*)d_in[15];
  const float* d2b = (const float*)d_in[16];
  const int* esrc  = (const int*)d_in[17];
  const int* edst  = (const int*)d_in[18];

  float* hs1 = (float*)d_ws;                       // 256*512*32 f32 = 16 MB
  float* hs2 = hs1 + (size_t)NG * NP * 32;         // +16 MB
  float* outp = (float*)d_out;

  hipFuncSetAttribute(reinterpret_cast<const void*>(dgcnn_fused),
                      hipFuncAttributeMaxDynamicSharedMemorySize, SMEM_SZ);
  dgcnn_fused<<<NG, 1024, SMEM_SZ, stream>>>(x, W0, b0, W1, b1, W2, b2, W3, b3,
                                             c1w, c1b, c2w, c2b, d1w, d1b, d2w, d2b,
                                             esrc, edst, hs1, hs2, outp);
}